// Round 4
// baseline (959.462 us; speedup 1.0000x reference)
//
#include <hip/hip_runtime.h>
#include <hip/hip_bf16.h>

#define E_ 8
#define D_ 1024
#define F_ 4096
#define K_ 2
#define ALIGN_ 256   // per-expert row alignment

typedef __attribute__((ext_vector_type(8))) short short8;
typedef __attribute__((ext_vector_type(4))) float f32x4;

__device__ __forceinline__ unsigned f2bf(float f){
  union { __hip_bfloat16 h; unsigned short u; } c;
  c.h = __float2bfloat16(f);
  return (unsigned)c.u;
}

__device__ __forceinline__ float bf2f(unsigned u){
  union { float f; unsigned u; } c;
  c.u = u << 16;
  return c.f;
}

__device__ __forceinline__ short8 cvt8(float4 a, float4 b){
  short8 r;
  r[0]=(short)f2bf(a.x); r[1]=(short)f2bf(a.y); r[2]=(short)f2bf(a.z); r[3]=(short)f2bf(a.w);
  r[4]=(short)f2bf(b.x); r[5]=(short)f2bf(b.y); r[6]=(short)f2bf(b.z); r[7]=(short)f2bf(b.w);
  return r;
}

template<bool B16>
__device__ __forceinline__ short8 loadw8(const void* __restrict__ base, size_t off){
  if constexpr (B16) {
    return *reinterpret_cast<const short8*>(reinterpret_cast<const __hip_bfloat16*>(base) + off);
  } else {
    const float4* p = reinterpret_cast<const float4*>(reinterpret_cast<const float*>(base) + off);
    float4 a = p[0]; float4 b = p[1];
    return cvt8(a, b);
  }
}

__device__ __forceinline__ float gelu_f(float v){
  const float c0 = 0.7978845608028654f;   // sqrt(2/pi)
  float z = c0 * (v + 0.044715f * v * v * v);
  float e = __expf(2.0f * z);
  float t = 1.0f - 2.0f / (1.0f + e);     // tanh(z), stable for |z| large
  return 0.5f * v * (1.0f + t);
}

__device__ __forceinline__ void gload16(const void* gsrc, void* ldst){
  __builtin_amdgcn_global_load_lds(
      (const __attribute__((address_space(1))) unsigned int*)gsrc,
      (__attribute__((address_space(3))) unsigned int*)ldst, 16, 0, 0);
}

// ---------------- gating ----------------
__global__ void gate_kernel(const float* __restrict__ x, const float* __restrict__ gw,
                            int* __restrict__ tidx, float* __restrict__ tw,
                            int* __restrict__ counts, int T){
  int wid = threadIdx.x >> 6, lane = threadIdx.x & 63;
  int t = blockIdx.x * 4 + wid;
  if (t >= T) return;
  const float* xr = x + (size_t)t * D_;
  double acc[E_];
  #pragma unroll
  for (int e = 0; e < E_; ++e) acc[e] = 0.0;
  #pragma unroll
  for (int j = 0; j < 16; ++j){
    float xv = xr[j*64 + lane];
    #pragma unroll
    for (int e = 0; e < E_; ++e)
      acc[e] += (double)xv * (double)gw[e*D_ + j*64 + lane];
  }
  #pragma unroll
  for (int e = 0; e < E_; ++e){
    #pragma unroll
    for (int off = 32; off >= 1; off >>= 1)
      acc[e] += __shfl_xor(acc[e], off);
  }
  if (lane == 0){
    float l[E_];
    #pragma unroll
    for (int e = 0; e < E_; ++e) l[e] = (float)acc[e];
    int i0 = 0; float v0 = l[0];
    #pragma unroll
    for (int e = 1; e < E_; ++e) if (l[e] > v0){ v0 = l[e]; i0 = e; }
    int i1 = -1; float v1 = -1e30f;
    #pragma unroll
    for (int e = 0; e < E_; ++e) if (e != i0 && l[e] > v1){ v1 = l[e]; i1 = e; }
    float e1 = expf(v1 - v0);
    float s = 1.0f + e1;
    tidx[2*t] = i0; tidx[2*t+1] = i1;
    tw[2*t] = 1.0f / s; tw[2*t+1] = e1 / s;
    atomicAdd(&counts[i0], 1);
    atomicAdd(&counts[i1], 1);
  }
}

__global__ void scan_kernel(const int* counts, int* aligned){
  if (threadIdx.x == 0 && blockIdx.x == 0){
    int s = 0;
    for (int e = 0; e < E_; ++e){ aligned[e] = s; s += ((counts[e] + ALIGN_ - 1) / ALIGN_) * ALIGN_; }
    aligned[E_] = s;
  }
}

// ---------------- fused scatter + gather: assign slots, copy x row (bf16) per assignment ----------------
__global__ void scatgath_kernel(const float* __restrict__ x,
                                const int* __restrict__ tidx,
                                const int* __restrict__ aligned, int* __restrict__ cursors,
                                int* __restrict__ tokSlot,
                                __hip_bfloat16* __restrict__ Abuf){
  int t = blockIdx.x;
  __shared__ int s_slot[K_];
  if (threadIdx.x < K_){
    int e = tidx[K_*t + threadIdx.x];
    int pos = aligned[e] + atomicAdd(&cursors[e], 1);
    tokSlot[K_*t + threadIdx.x] = pos;
    s_slot[threadIdx.x] = pos;
  }
  __syncthreads();
  const float4* src = reinterpret_cast<const float4*>(x + (size_t)t * D_) + threadIdx.x*2;
  float4 v0 = src[0], v1 = src[1];
  uint4 p;
  p.x = f2bf(v0.x) | (f2bf(v0.y) << 16);
  p.y = f2bf(v0.z) | (f2bf(v0.w) << 16);
  p.z = f2bf(v1.x) | (f2bf(v1.y) << 16);
  p.w = f2bf(v1.z) | (f2bf(v1.w) << 16);
  #pragma unroll
  for (int k = 0; k < K_; ++k)
    *(reinterpret_cast<uint4*>(reinterpret_cast<unsigned short*>(Abuf) + (size_t)s_slot[k]*D_) + threadIdx.x) = p;
}

// ---------------- weight fp32 -> bf16 ----------------
__global__ void cvtw_kernel(const float* __restrict__ src, __hip_bfloat16* __restrict__ dst, int n4){
  int stride = gridDim.x * blockDim.x;
  for (int i = blockIdx.x * blockDim.x + threadIdx.x; i < n4; i += stride){
    float4 v = reinterpret_cast<const float4*>(src)[i];
    uint2 p;
    p.x = f2bf(v.x) | (f2bf(v.y) << 16);
    p.y = f2bf(v.z) | (f2bf(v.w) << 16);
    reinterpret_cast<uint2*>(dst)[i] = p;
  }
}

// ---------------- final combine: out[t] = sum_k w_k * (Y[slot_k] + b_proj[e_k]) ----------------
__global__ void combine_kernel(const unsigned short* __restrict__ Ybuf,
                               const int* __restrict__ tidx, const float* __restrict__ tw,
                               const int* __restrict__ tokSlot,
                               const float* __restrict__ bpj,
                               float* __restrict__ out){
  int t = blockIdx.x;
  int d = threadIdx.x * 4;
  int e0 = tidx[2*t], e1 = tidx[2*t+1];
  float w0 = tw[2*t], w1 = tw[2*t+1];
  int s0 = tokSlot[2*t], s1 = tokSlot[2*t+1];
  uint2 ya = *reinterpret_cast<const uint2*>(Ybuf + (size_t)s0*D_ + d);
  uint2 yb = *reinterpret_cast<const uint2*>(Ybuf + (size_t)s1*D_ + d);
  float4 b0 = *reinterpret_cast<const float4*>(bpj + (size_t)e0*D_ + d);
  float4 b1 = *reinterpret_cast<const float4*>(bpj + (size_t)e1*D_ + d);
  float4 r;
  r.x = w0*(bf2f(ya.x & 0xffffu) + b0.x) + w1*(bf2f(yb.x & 0xffffu) + b1.x);
  r.y = w0*(bf2f(ya.x >> 16)     + b0.y) + w1*(bf2f(yb.x >> 16)     + b1.y);
  r.z = w0*(bf2f(ya.y & 0xffffu) + b0.z) + w1*(bf2f(yb.y & 0xffffu) + b1.z);
  r.w = w0*(bf2f(ya.y >> 16)     + b0.w) + w1*(bf2f(yb.y >> 16)     + b1.w);
  *reinterpret_cast<float4*>(out + (size_t)t*D_ + d) = r;
}

// ---------------- counted-vmcnt phase-split 128x128 GEMM (T3+T4+T5, K-half planes) ----------------
// LDS plane: [128 rows][32 bf16], row-slot XOR swizzle: slot' = slot ^ (r&3) ^ ((r>>2)&3)

__device__ __forceinline__ short8 fragread(const char* plane, int row, int lg){
  int byte = (row << 6) + ((lg ^ (row & 3) ^ ((row >> 2) & 3)) << 4);
  return *reinterpret_cast<const short8*>(plane + byte);
}

__device__ __forceinline__ void stage_plane(const __hip_bfloat16* g, int ldk, int k0,
                                            char* plane, int tid){
  #pragma unroll
  for (int i = 0; i < 2; ++i){
    int flat = i*4096 + tid*16;
    int r = flat >> 6;
    int j = ((flat >> 4) & 3) ^ (r & 3) ^ ((r >> 2) & 3);
    gload16((const char*)(g + (size_t)r*ldk + k0 + j*8),
            plane + i*4096 + (tid & ~63)*16);
  }
}

__device__ __forceinline__ void compute_group(const char* pA, const char* pB,
                                              f32x4 acc[4][4], int ra, int rb, int lg){
  short8 a[4], b[4];
  #pragma unroll
  for (int m = 0; m < 4; ++m) a[m] = fragread(pA, ra + m*16, lg);
  #pragma unroll
  for (int n = 0; n < 4; ++n) b[n] = fragread(pB, rb + n*16, lg);
  __builtin_amdgcn_s_setprio(1);
  #pragma unroll
  for (int m = 0; m < 4; ++m)
    #pragma unroll
    for (int n = 0; n < 4; ++n)
      acc[m][n] = __builtin_amdgcn_mfma_f32_16x16x32_bf16(b[n], a[m], acc[m][n], 0, 0, 0);
  __builtin_amdgcn_s_setprio(0);
}

template<bool PH1>
__global__ __launch_bounds__(256, 2) void gemm8_kernel(
    const __hip_bfloat16* __restrict__ Abuf,   // [rows][KA]
    const __hip_bfloat16* __restrict__ W,      // [E][NT][KA]
    const float* __restrict__ bias,            // [E][NT] (PH1)
    const int* __restrict__ aligned,
    unsigned short* __restrict__ Out16)
{
  constexpr int KA  = PH1 ? D_ : F_;
  constexpr int NT  = PH1 ? F_ : D_;
  constexpr int NKT = KA / 64;
  constexpr int NX  = NT / 128;

  __shared__ __align__(16) char sA[2][2][8192];
  __shared__ __align__(16) char sB[2][2][8192];

  int total = aligned[E_];
  int nwg = gridDim.x;
  int bid = blockIdx.x;
  int swz = (bid & 7) * (nwg >> 3) + (bid >> 3);   // nwg divisible by 8
  int NYt = nwg / NX;
  int xt = swz / NYt, yt = swz - xt*NYt;           // col-major within XCD chunk: B panels L2-resident
  int rowBase = yt * 128;
  if (rowBase >= total) return;
  int e = 0;
  #pragma unroll
  for (int i = 1; i < E_; ++i) if (rowBase >= aligned[i]) e = i;
  int nBase = xt * 128;

  const int tid = threadIdx.x;
  const int lane = tid & 63, wid = tid >> 6;
  const int lr = lane & 15, lg = lane >> 4;
  const int wr = wid >> 1, wc = wid & 1;

  const __hip_bfloat16* Ab = Abuf + (size_t)rowBase * KA;
  const __hip_bfloat16* Bb = W + ((size_t)e*NT + nBase) * KA;

  f32x4 acc[4][4];
  #pragma unroll
  for (int m = 0; m < 4; ++m)
    #pragma unroll
    for (int n = 0; n < 4; ++n) acc[m][n] = (f32x4){0.f,0.f,0.f,0.f};

  // prologue: tile 0, both K-half groups, into buf 0. issue order per tile: A0,B0,A1,B1
  stage_plane(Ab, KA, 0,  sA[0][0], tid);
  stage_plane(Bb, KA, 0,  sB[0][0], tid);
  stage_plane(Ab, KA, 32, sA[0][1], tid);
  stage_plane(Bb, KA, 32, sB[0][1], tid);

  const int ra = wr*64 + lr, rb = wc*64 + lr;

  for (int t = 0; t < NKT; ++t){
    const int buf = t & 1;
    const bool more = (t + 1 < NKT);
    const int k1 = (t + 1) * 64;
    // ---- group 0 (K elems [t*64, t*64+32)) ----
    asm volatile("s_waitcnt vmcnt(4)" ::: "memory");
    __builtin_amdgcn_s_barrier();
    if (more){
      stage_plane(Ab, KA, k1,      sA[buf^1][0], tid);
      stage_plane(Bb, KA, k1,      sB[buf^1][0], tid);
    }
    compute_group(sA[buf][0], sB[buf][0], acc, ra, rb, lg);
    // ---- group 1 (K elems [t*64+32, t*64+64)) ----
    if (more){ asm volatile("s_waitcnt vmcnt(4)" ::: "memory"); }
    else     { asm volatile("s_waitcnt vmcnt(0)" ::: "memory"); }
    __builtin_amdgcn_s_barrier();
    if (more){
      stage_plane(Ab, KA, k1 + 32, sA[buf^1][1], tid);
      stage_plane(Bb, KA, k1 + 32, sB[buf^1][1], tid);
    }
    compute_group(sA[buf][1], sB[buf][1], acc, ra, rb, lg);
  }

  // epilogue: rows rowBase+wr*64+m*16+lr ; cols nBase+wc*64+n*16+lg*4+{0..3}
  if constexpr (PH1){
    #pragma unroll
    for (int n = 0; n < 4; ++n){
      int gc = nBase + wc*64 + n*16 + lg*4;
      float4 b4 = *reinterpret_cast<const float4*>(bias + (size_t)e*F_ + gc);
      #pragma unroll
      for (int m = 0; m < 4; ++m){
        int grow = rowBase + wr*64 + m*16 + lr;
        uint2 p;
        p.x = f2bf(gelu_f(acc[m][n][0] + b4.x)) | (f2bf(gelu_f(acc[m][n][1] + b4.y)) << 16);
        p.y = f2bf(gelu_f(acc[m][n][2] + b4.z)) | (f2bf(gelu_f(acc[m][n][3] + b4.w)) << 16);
        *reinterpret_cast<uint2*>(Out16 + (size_t)grow * F_ + gc) = p;
      }
    }
  } else {
    #pragma unroll
    for (int n = 0; n < 4; ++n){
      int gc = nBase + wc*64 + n*16 + lg*4;
      #pragma unroll
      for (int m = 0; m < 4; ++m){
        int grow = rowBase + wr*64 + m*16 + lr;
        uint2 p;
        p.x = f2bf(acc[m][n][0]) | (f2bf(acc[m][n][1]) << 16);
        p.y = f2bf(acc[m][n][2]) | (f2bf(acc[m][n][3]) << 16);
        *reinterpret_cast<uint2*>(Out16 + (size_t)grow * D_ + gc) = p;
      }
    }
  }
}

// ================= fallback kernels (ws too small for the bf16 two-pass path) =================
__global__ void init_kernel(int* rowTok, float* rowW, int* counts, int* cursors, int nSlots){
  int i = blockIdx.x * blockDim.x + threadIdx.x;
  if (i < nSlots){ rowTok[i] = 0; rowW[i] = 0.0f; }
  if (i < E_){ counts[i] = 0; cursors[i] = 0; }
}

__global__ void scatter_kernel(const int* __restrict__ tidx, const float* __restrict__ tw,
                               const int* __restrict__ aligned, int* cursors,
                               int* __restrict__ rowTok, float* __restrict__ rowW,
                               int* __restrict__ tokSlot, int T){
  int t = blockIdx.x * blockDim.x + threadIdx.x;
  if (t >= T) return;
  for (int k = 0; k < K_; ++k){
    int e = tidx[2*t + k];
    int pos = aligned[e] + atomicAdd(&cursors[e], 1);
    rowTok[pos] = t;
    rowW[pos] = tw[2*t + k];
    tokSlot[2*t + k] = pos;
  }
}

__global__ void gather_kernel(const float* __restrict__ x, const int* __restrict__ rowTok,
                              __hip_bfloat16* __restrict__ Abuf){
  int slot = blockIdx.x;
  int t = rowTok[slot];
  const float4* src = reinterpret_cast<const float4*>(x + (size_t)t * D_);
  uint2* dst = reinterpret_cast<uint2*>(reinterpret_cast<unsigned short*>(Abuf) + (size_t)slot * D_);
  float4 v = src[threadIdx.x];
  uint2 p;
  p.x = f2bf(v.x) | (f2bf(v.y) << 16);
  p.y = f2bf(v.z) | (f2bf(v.w) << 16);
  dst[threadIdx.x] = p;
}

// round-3 m97-style GEMM, fp32 weights (reg-staged B)
template<bool PH1>
__global__ __launch_bounds__(256, 4) void gemm_old_kernel(
    const __hip_bfloat16* __restrict__ Abuf,
    const float* __restrict__ Wf,
    const float* __restrict__ bias,
    const int* __restrict__ aligned,
    unsigned short* __restrict__ Out16)
{
  constexpr int KA = PH1 ? D_ : F_;
  constexpr int NT = PH1 ? F_ : D_;
  constexpr int NK = KA / 64;

  __shared__ char sA[128*128];
  __shared__ char sB[128*128];

  int rowBase = blockIdx.y * 128;
  if (rowBase >= aligned[E_]) return;
  int e = 0;
  #pragma unroll
  for (int i = 1; i < E_; ++i) if (rowBase >= aligned[i]) e = i;

  int nBase = blockIdx.x * 128;
  const int tid = threadIdx.x;
  const int wid = tid >> 6, lane = tid & 63;
  const int lr = lane & 15, lg = lane >> 4;
  const int wr = wid >> 1, wc = wid & 1;

  const size_t Wrow0 = (size_t)e * NT + nBase;

  f32x4 acc[4][4];
  #pragma unroll
  for (int m = 0; m < 4; ++m)
    #pragma unroll
    for (int n = 0; n < 4; ++n) acc[m][n] = (f32x4){0.f,0.f,0.f,0.f};

  for (int kt = 0; kt < NK; ++kt){
    int k0 = kt * 64;
    #pragma unroll
    for (int i = 0; i < 4; ++i){
      int flat = i*4096 + wid*1024 + lane*16;
      int row  = flat >> 7;
      int colb = flat & 127;
      int scol = colb ^ ((row & 7) << 4);
      const char* src = (const char*)(Abuf + (size_t)(rowBase + row) * KA + k0) + scol;
      gload16(src, sA + i*4096 + wid*1024);
    }
    #pragma unroll
    for (int i = 0; i < 8; ++i){
      int f4  = i*256 + tid;
      int row = f4 >> 4;
      int c4  = f4 & 15;
      float4 v = *reinterpret_cast<const float4*>(Wf + (Wrow0 + row) * KA + k0 + c4*4);
      uint2 p;
      p.x = f2bf(v.x) | (f2bf(v.y) << 16);
      p.y = f2bf(v.z) | (f2bf(v.w) << 16);
      int byte = row*128 + c4*8;
      *reinterpret_cast<uint2*>(sB + (byte ^ ((row & 7) << 4))) = p;
    }
    __syncthreads();
    #pragma unroll
    for (int ks = 0; ks < 2; ++ks){
      short8 a[4], b[4];
      #pragma unroll
      for (int m = 0; m < 4; ++m){
        int row = wr*64 + m*16 + lr;
        a[m] = *reinterpret_cast<const short8*>(sA + row*128 + ((ks*64 + lg*16) ^ ((row & 7) << 4)));
      }
      #pragma unroll
      for (int n = 0; n < 4; ++n){
        int row = wc*64 + n*16 + lr;
        b[n] = *reinterpret_cast<const short8*>(sB + row*128 + ((ks*64 + lg*16) ^ ((row & 7) << 4)));
      }
      #pragma unroll
      for (int m = 0; m < 4; ++m)
        #pragma unroll
        for (int n = 0; n < 4; ++n)
          acc[m][n] = __builtin_amdgcn_mfma_f32_16x16x32_bf16(b[n], a[m], acc[m][n], 0, 0, 0);
    }
    __syncthreads();
  }

  int colBase = nBase + wc*64;
  if constexpr (PH1){
    #pragma unroll
    for (int n = 0; n < 4; ++n){
      int gc = colBase + n*16 + lg*4;
      float4 b4 = *reinterpret_cast<const float4*>(bias + (size_t)e*F_ + gc);
      #pragma unroll
      for (int m = 0; m < 4; ++m){
        int tkn = rowBase + wr*64 + m*16 + lr;
        uint2 p;
        p.x = f2bf(gelu_f(acc[m][n][0] + b4.x)) | (f2bf(gelu_f(acc[m][n][1] + b4.y)) << 16);
        p.y = f2bf(gelu_f(acc[m][n][2] + b4.z)) | (f2bf(gelu_f(acc[m][n][3] + b4.w)) << 16);
        *reinterpret_cast<uint2*>(Out16 + (size_t)tkn * F_ + gc) = p;
      }
    }
  } else {
    #pragma unroll
    for (int n = 0; n < 4; ++n){
      int gc = colBase + n*16 + lg*4;
      #pragma unroll
      for (int m = 0; m < 4; ++m){
        int slot = rowBase + wr*64 + m*16 + lr;
        uint2 p;
        p.x = f2bf(acc[m][n][0]) | (f2bf(acc[m][n][1]) << 16);
        p.y = f2bf(acc[m][n][2]) | (f2bf(acc[m][n][3]) << 16);
        *reinterpret_cast<uint2*>(Out16 + (size_t)slot * D_ + gc) = p;
      }
    }
  }
}

extern "C" void kernel_launch(void* const* d_in, const int* in_sizes, int n_in,
                              void* d_out, int out_size, void* d_ws, size_t ws_size,
                              hipStream_t stream){
  const float* x   = (const float*)d_in[0];
  const float* gw  = (const float*)d_in[1];
  const float* wfc = (const float*)d_in[2];
  const float* bfc = (const float*)d_in[3];
  const float* wpj = (const float*)d_in[4];
  const float* bpj = (const float*)d_in[5];
  float* out = (float*)d_out;

  int T = in_sizes[0] / D_;              // 8192
  int nAssign = T * K_;
  int nSlotsMax = nAssign + E_ * ALIGN_; // 18432
  int rowTiles = nSlotsMax / 128;        // 144

  char* ws = (char*)d_ws;
  size_t o = 0;
  int*   tidx    = (int*)(ws + o); o += (size_t)nAssign * 4;
  float* tw      = (float*)(ws + o); o += (size_t)nAssign * 4;
  int*   counts  = (int*)(ws + o); o += 256;
  int*   cursors = (int*)(ws + o); o += 256;   // contiguous with counts: one memset
  int*   aligned = (int*)(ws + o); o += 256;
  int*   tokSlot = (int*)(ws + o); o += (size_t)nAssign * 4;
  int*   rowTok  = (int*)(ws + o); o += (size_t)nSlotsMax * 4;   // fallback only
  float* rowW    = (float*)(ws + o); o += (size_t)nSlotsMax * 4; // fallback only
  o = (o + 255) & ~(size_t)255;

  size_t abytes = (size_t)nSlotsMax * D_ * 2;   // Abuf; reused as Ybuf after GEMM1
  size_t hbytes = (size_t)nSlotsMax * F_ * 2;
  size_t wbytes = (size_t)E_ * F_ * D_ * 2;

  __hip_bfloat16* Abuf = (__hip_bfloat16*)(ws + o); o += abytes;
  __hip_bfloat16* Hbuf = (__hip_bfloat16*)(ws + o); o += hbytes;
  size_t o_w16 = o;
  __hip_bfloat16* w16 = (__hip_bfloat16*)(ws + o_w16);

  bool newPath = (ws_size >= o_w16 + wbytes);   // ~253 MB
  bool oldPath = (ws_size >= o_w16);            // ~189 MB (fp32-weight GEMMs)

  if (newPath){
    hipMemsetAsync(counts, 0, 512, stream);
    gate_kernel<<<(T + 3)/4, 256, 0, stream>>>(x, gw, tidx, tw, counts, T);
    scan_kernel<<<1, 64, 0, stream>>>(counts, aligned);
    scatgath_kernel<<<T, 128, 0, stream>>>(x, tidx, aligned, cursors, tokSlot, Abuf);
    int n4 = E_ * F_ * D_ / 4;
    unsigned short* Ybuf = (unsigned short*)Abuf;
    cvtw_kernel<<<2048, 256, 0, stream>>>(wfc, w16, n4);
    gemm8_kernel<true><<<(F_/128) * rowTiles, 256, 0, stream>>>(
        Abuf, w16, bfc, aligned, (unsigned short*)Hbuf);
    cvtw_kernel<<<2048, 256, 0, stream>>>(wpj, w16, n4);
    gemm8_kernel<false><<<(D_/128) * rowTiles, 256, 0, stream>>>(
        Hbuf, w16, bpj, aligned, Ybuf);
    combine_kernel<<<T, 256, 0, stream>>>(Ybuf, tidx, tw, tokSlot, bpj, out);
  } else if (oldPath){
    init_kernel<<<(nSlotsMax + 255)/256, 256, 0, stream>>>(rowTok, rowW, counts, cursors, nSlotsMax);
    gate_kernel<<<(T + 3)/4, 256, 0, stream>>>(x, gw, tidx, tw, counts, T);
    scan_kernel<<<1, 64, 0, stream>>>(counts, aligned);
    scatter_kernel<<<(T + 255)/256, 256, 0, stream>>>(tidx, tw, aligned, cursors, rowTok, rowW, tokSlot, T);
    gather_kernel<<<nSlotsMax, 256, 0, stream>>>(x, rowTok, Abuf);
    unsigned short* Ybuf = (unsigned short*)Abuf;
    gemm_old_kernel<true><<<dim3(F_/128, rowTiles), 256, 0, stream>>>(
        Abuf, wfc, bfc, aligned, (unsigned short*)Hbuf);
    gemm_old_kernel<false><<<dim3(D_/128, rowTiles), 256, 0, stream>>>(
        Hbuf, wpj, bpj, aligned, Ybuf);
    combine_kernel<<<T, 256, 0, stream>>>(Ybuf, tidx, tw, tokSlot, bpj, out);
  }
  // (ws below ~189 MB unsupported; harness-provided ws has been >= this in all rounds)
}

// Round 5
// 753.608 us; speedup vs baseline: 1.2732x; 1.2732x over previous
//
#include <hip/hip_runtime.h>
#include <hip/hip_bf16.h>

#define E_ 8
#define D_ 1024
#define F_ 4096
#define K_ 2

typedef __attribute__((ext_vector_type(8))) short short8;
typedef __attribute__((ext_vector_type(4))) float f32x4;

__device__ __forceinline__ unsigned f2bf(float f){
  union { __hip_bfloat16 h; unsigned short u; } c;
  c.h = __float2bfloat16(f);
  return (unsigned)c.u;
}

__device__ __forceinline__ float bf2f(unsigned u){
  union { float f; unsigned u; } c;
  c.u = u << 16;
  return c.f;
}

__device__ __forceinline__ float gelu_f(float v){
  const float c0 = 0.7978845608028654f;   // sqrt(2/pi)
  float z = c0 * (v + 0.044715f * v * v * v);
  float e = __expf(2.0f * z);
  float t = 1.0f - 2.0f / (1.0f + e);     // tanh(z), stable for |z| large
  return 0.5f * v * (1.0f + t);
}

__device__ __forceinline__ void gload16(const void* gsrc, void* ldst){
  __builtin_amdgcn_global_load_lds(
      (const __attribute__((address_space(1))) unsigned int*)gsrc,
      (__attribute__((address_space(3))) unsigned int*)ldst, 16, 0, 0);
}

// ---------------- gating: top-2 + softmax (fp64 accum to match fp32-ref ranking) ----------------
__global__ void gate_kernel(const float* __restrict__ x, const float* __restrict__ gw,
                            int* __restrict__ tidx, float* __restrict__ tw,
                            int* __restrict__ counts, int T){
  int wid = threadIdx.x >> 6, lane = threadIdx.x & 63;
  int t = blockIdx.x * 4 + wid;
  if (t >= T) return;
  const float* xr = x + (size_t)t * D_;
  double acc[E_];
  #pragma unroll
  for (int e = 0; e < E_; ++e) acc[e] = 0.0;
  #pragma unroll
  for (int j = 0; j < 16; ++j){
    float xv = xr[j*64 + lane];
    #pragma unroll
    for (int e = 0; e < E_; ++e)
      acc[e] += (double)xv * (double)gw[e*D_ + j*64 + lane];
  }
  #pragma unroll
  for (int e = 0; e < E_; ++e){
    #pragma unroll
    for (int off = 32; off >= 1; off >>= 1)
      acc[e] += __shfl_xor(acc[e], off);
  }
  if (lane == 0){
    float l[E_];
    #pragma unroll
    for (int e = 0; e < E_; ++e) l[e] = (float)acc[e];
    int i0 = 0; float v0 = l[0];
    #pragma unroll
    for (int e = 1; e < E_; ++e) if (l[e] > v0){ v0 = l[e]; i0 = e; }
    int i1 = -1; float v1 = -1e30f;
    #pragma unroll
    for (int e = 0; e < E_; ++e) if (e != i0 && l[e] > v1){ v1 = l[e]; i1 = e; }
    float e1 = expf(v1 - v0);
    float s = 1.0f + e1;
    tidx[2*t] = i0; tidx[2*t+1] = i1;
    tw[2*t] = 1.0f / s; tw[2*t+1] = e1 / s;
    atomicAdd(&counts[i0], 1);
    atomicAdd(&counts[i1], 1);
  }
}

// ---------------- fused scatter + gather: slot assignment (prefix from counts) + bf16 row copy ----------------
__global__ void scatgath_kernel(const float* __restrict__ x,
                                const int* __restrict__ tidx,
                                const int* __restrict__ counts, int* __restrict__ cursors,
                                int* __restrict__ tokSlot,
                                __hip_bfloat16* __restrict__ Abuf){
  int t = blockIdx.x;
  __shared__ int s_slot[K_];
  if (threadIdx.x < K_){
    int e = tidx[K_*t + threadIdx.x];
    int base = 0;
    #pragma unroll
    for (int i = 0; i < E_; ++i)
      base += (i < e) ? ((counts[i] + 127) & ~127) : 0;
    int pos = base + atomicAdd(&cursors[e], 1);
    tokSlot[K_*t + threadIdx.x] = pos;
    s_slot[threadIdx.x] = pos;
  }
  __syncthreads();
  const float4* src = reinterpret_cast<const float4*>(x + (size_t)t * D_) + threadIdx.x*2;
  float4 v0 = src[0], v1 = src[1];
  uint4 p;
  p.x = f2bf(v0.x) | (f2bf(v0.y) << 16);
  p.y = f2bf(v0.z) | (f2bf(v0.w) << 16);
  p.z = f2bf(v1.x) | (f2bf(v1.y) << 16);
  p.w = f2bf(v1.z) | (f2bf(v1.w) << 16);
  #pragma unroll
  for (int k = 0; k < K_; ++k)
    *(reinterpret_cast<uint4*>(reinterpret_cast<unsigned short*>(Abuf) + (size_t)s_slot[k]*D_) + threadIdx.x) = p;
}

// ---------------- weight fp32 -> bf16 ----------------
__global__ void cvtw_kernel(const float* __restrict__ src, __hip_bfloat16* __restrict__ dst, int n4){
  int stride = gridDim.x * blockDim.x;
  for (int i = blockIdx.x * blockDim.x + threadIdx.x; i < n4; i += stride){
    float4 v = reinterpret_cast<const float4*>(src)[i];
    uint2 p;
    p.x = f2bf(v.x) | (f2bf(v.y) << 16);
    p.y = f2bf(v.z) | (f2bf(v.w) << 16);
    reinterpret_cast<uint2*>(dst)[i] = p;
  }
}

// ---------------- final combine: out[t] = sum_k w_k * (Y[slot_k] + b_proj[e_k]) ----------------
__global__ void combine_kernel(const unsigned short* __restrict__ Ybuf,
                               const int* __restrict__ tidx, const float* __restrict__ tw,
                               const int* __restrict__ tokSlot,
                               const float* __restrict__ bpj,
                               float* __restrict__ out){
  int t = blockIdx.x;
  int d = threadIdx.x * 4;
  int e0 = tidx[2*t], e1 = tidx[2*t+1];
  float w0 = tw[2*t], w1 = tw[2*t+1];
  int s0 = tokSlot[2*t], s1 = tokSlot[2*t+1];
  uint2 ya = *reinterpret_cast<const uint2*>(Ybuf + (size_t)s0*D_ + d);
  uint2 yb = *reinterpret_cast<const uint2*>(Ybuf + (size_t)s1*D_ + d);
  float4 b0 = *reinterpret_cast<const float4*>(bpj + (size_t)e0*D_ + d);
  float4 b1 = *reinterpret_cast<const float4*>(bpj + (size_t)e1*D_ + d);
  float4 r;
  r.x = w0*(bf2f(ya.x & 0xffffu) + b0.x) + w1*(bf2f(yb.x & 0xffffu) + b1.x);
  r.y = w0*(bf2f(ya.x >> 16)     + b0.y) + w1*(bf2f(yb.x >> 16)     + b1.y);
  r.z = w0*(bf2f(ya.y & 0xffffu) + b0.z) + w1*(bf2f(yb.y & 0xffffu) + b1.z);
  r.w = w0*(bf2f(ya.y >> 16)     + b0.w) + w1*(bf2f(yb.y >> 16)     + b1.w);
  *reinterpret_cast<float4*>(out + (size_t)t*D_ + d) = r;
}

// ---------------- 128x128 GEMM (round-3 m97 structure + XCD row-chunk swizzle) ----------------
// PH1: H = gelu(A wfc^T + b) -> bf16 Hbuf[slot][F]
// PH2: Y = H wproj^T         -> bf16 Ybuf[slot][D]   (bias+route applied in combine)
template<bool WB16, bool PH1>
__global__ __launch_bounds__(256, 4) void gemm_kernel(
    const __hip_bfloat16* __restrict__ Abuf,   // [rows][KA] bf16
    const void* __restrict__ W,                // [E][NT][KA] bf16 or fp32
    const float* __restrict__ bias,            // [E][NT] (PH1 only)
    const int* __restrict__ counts,
    unsigned short* __restrict__ Out16)
{
  constexpr int KA = PH1 ? D_ : F_;
  constexpr int NT = PH1 ? F_ : D_;
  constexpr int NK = KA / 64;
  constexpr int NX = NT / 128;

  __shared__ char sA[128*128];
  __shared__ char sB[128*128];

  // prefix over counts (128-aligned per-expert regions)
  int pre[E_]; int total = 0;
  #pragma unroll
  for (int i = 0; i < E_; ++i){ pre[i] = total; total += (counts[i] + 127) & ~127; }

  // bijective XCD row-chunk swizzle: XCD c = bid&7 owns contiguous wgid chunk
  // -> each XCD processes ~17 contiguous row-tiles x ALL column-tiles
  //    (A/H tile fetched once per XCD; same rows hit the same XCD in both GEMMs)
  int q = gridDim.x >> 3;                       // gridDim.x divisible by 8
  int wgid = (blockIdx.x & 7) * q + (blockIdx.x >> 3);
  int yt = wgid / NX, xt = wgid - yt * NX;      // columns fastest within chunk
  int rowBase = yt * 128;
  if (rowBase >= total) return;
  int e = 0;
  #pragma unroll
  for (int i = 1; i < E_; ++i) if (rowBase >= pre[i]) e = i;
  int nBase = xt * 128;

  const int tid = threadIdx.x;
  const int wid = tid >> 6, lane = tid & 63;
  const int lr = lane & 15, lg = lane >> 4;
  const int wr = wid >> 1, wc = wid & 1;

  const unsigned short* Wb = (const unsigned short*)W;
  const float* Wf = (const float*)W;
  const size_t Wrow0 = (size_t)e * NT + nBase;

  f32x4 acc[4][4];
  #pragma unroll
  for (int m = 0; m < 4; ++m)
    #pragma unroll
    for (int n = 0; n < 4; ++n) acc[m][n] = (f32x4){0.f,0.f,0.f,0.f};

  for (int kt = 0; kt < NK; ++kt){
    int k0 = kt * 64;
    // ---- stage A tile via global_load_lds (linear dest, inverse-swizzled source) ----
    #pragma unroll
    for (int i = 0; i < 4; ++i){
      int flat = i*4096 + wid*1024 + lane*16;
      int row  = flat >> 7;
      int colb = flat & 127;
      int scol = colb ^ ((row & 7) << 4);
      const char* src = (const char*)(Abuf + (size_t)(rowBase + row) * KA + k0) + scol;
      gload16(src, sA + i*4096 + wid*1024);
    }
    // ---- stage B tile ----
    if constexpr (WB16){
      #pragma unroll
      for (int i = 0; i < 4; ++i){
        int flat = i*4096 + wid*1024 + lane*16;
        int row  = flat >> 7;
        int colb = flat & 127;
        int scol = colb ^ ((row & 7) << 4);
        const char* src = (const char*)(Wb + (Wrow0 + row) * KA + k0) + scol;
        gload16(src, sB + i*4096 + wid*1024);
      }
    } else {
      // reg-stage fp32 -> bf16, write-side swizzle
      #pragma unroll
      for (int i = 0; i < 8; ++i){
        int f4  = i*256 + tid;      // float4 index: 128 rows x 16 per row
        int row = f4 >> 4;
        int c4  = f4 & 15;
        float4 v = *reinterpret_cast<const float4*>(Wf + (Wrow0 + row) * KA + k0 + c4*4);
        uint2 p;
        p.x = f2bf(v.x) | (f2bf(v.y) << 16);
        p.y = f2bf(v.z) | (f2bf(v.w) << 16);
        int byte = row*128 + c4*8;
        *reinterpret_cast<uint2*>(sB + (byte ^ ((row & 7) << 4))) = p;
      }
    }
    __syncthreads();
    // ---- compute (swapped operands: each thread holds 4 contiguous output cols) ----
    #pragma unroll
    for (int ks = 0; ks < 2; ++ks){
      short8 a[4], b[4];
      #pragma unroll
      for (int m = 0; m < 4; ++m){
        int row = wr*64 + m*16 + lr;
        a[m] = *reinterpret_cast<const short8*>(sA + row*128 + ((ks*64 + lg*16) ^ ((row & 7) << 4)));
      }
      #pragma unroll
      for (int n = 0; n < 4; ++n){
        int row = wc*64 + n*16 + lr;
        b[n] = *reinterpret_cast<const short8*>(sB + row*128 + ((ks*64 + lg*16) ^ ((row & 7) << 4)));
      }
      #pragma unroll
      for (int m = 0; m < 4; ++m)
        #pragma unroll
        for (int n = 0; n < 4; ++n)
          acc[m][n] = __builtin_amdgcn_mfma_f32_16x16x32_bf16(b[n], a[m], acc[m][n], 0, 0, 0);
    }
    __syncthreads();
  }

  // epilogue: rows rowBase+wr*64+m*16+lr ; cols nBase+wc*64+n*16+lg*4+{0..3}
  int colBase = nBase + wc*64;
  if constexpr (PH1){
    #pragma unroll
    for (int n = 0; n < 4; ++n){
      int gc = colBase + n*16 + lg*4;
      float4 b4 = *reinterpret_cast<const float4*>(bias + (size_t)e*F_ + gc);
      #pragma unroll
      for (int m = 0; m < 4; ++m){
        int grow = rowBase + wr*64 + m*16 + lr;
        uint2 p;
        p.x = f2bf(gelu_f(acc[m][n][0] + b4.x)) | (f2bf(gelu_f(acc[m][n][1] + b4.y)) << 16);
        p.y = f2bf(gelu_f(acc[m][n][2] + b4.z)) | (f2bf(gelu_f(acc[m][n][3] + b4.w)) << 16);
        *reinterpret_cast<uint2*>(Out16 + (size_t)grow * F_ + gc) = p;
      }
    }
  } else {
    #pragma unroll
    for (int n = 0; n < 4; ++n){
      int gc = colBase + n*16 + lg*4;
      #pragma unroll
      for (int m = 0; m < 4; ++m){
        int grow = rowBase + wr*64 + m*16 + lr;
        uint2 p;
        p.x = f2bf(acc[m][n][0]) | (f2bf(acc[m][n][1]) << 16);
        p.y = f2bf(acc[m][n][2]) | (f2bf(acc[m][n][3]) << 16);
        *reinterpret_cast<uint2*>(Out16 + (size_t)grow * D_ + gc) = p;
      }
    }
  }
}

extern "C" void kernel_launch(void* const* d_in, const int* in_sizes, int n_in,
                              void* d_out, int out_size, void* d_ws, size_t ws_size,
                              hipStream_t stream){
  const float* x   = (const float*)d_in[0];
  const float* gw  = (const float*)d_in[1];
  const float* wfc = (const float*)d_in[2];
  const float* bfc = (const float*)d_in[3];
  const float* wpj = (const float*)d_in[4];
  const float* bpj = (const float*)d_in[5];
  float* out = (float*)d_out;

  int T = in_sizes[0] / D_;              // 8192
  int nAssign = T * K_;
  int nSlotsMax = nAssign + E_ * 128;    // 17408
  int rowTiles = nSlotsMax / 128;        // 136

  char* ws = (char*)d_ws;
  size_t o = 0;
  int*   tidx    = (int*)(ws + o); o += (size_t)nAssign * 4;
  float* tw      = (float*)(ws + o); o += (size_t)nAssign * 4;
  int*   counts  = (int*)(ws + o); o += 256;
  int*   cursors = (int*)(ws + o); o += 256;   // contiguous with counts: one memset
  int*   tokSlot = (int*)(ws + o); o += (size_t)nAssign * 4;
  o = (o + 255) & ~(size_t)255;

  size_t abytes = (size_t)nSlotsMax * D_ * 2;   // Abuf; reused as Ybuf after GEMM1
  size_t hbytes = (size_t)nSlotsMax * F_ * 2;
  size_t wbytes = (size_t)E_ * F_ * D_ * 2;     // 67 MB per weight tensor (bf16)

  __hip_bfloat16* Abuf = (__hip_bfloat16*)(ws + o); o += abytes;
  __hip_bfloat16* Hbuf = (__hip_bfloat16*)(ws + o); o += hbytes;
  size_t o_w = o;
  __hip_bfloat16* wA = (__hip_bfloat16*)(ws + o_w);
  __hip_bfloat16* wB = (__hip_bfloat16*)(ws + o_w + wbytes);

  bool newPath = (ws_size >= o_w + 2*wbytes);   // ~313 MB: both weights converted upfront
  bool midPath = (ws_size >= o_w + wbytes);     // ~246 MB: one buffer, serial reuse
  // below that: fp32-weight GEMMs (~179 MB)

  int n4 = E_ * F_ * D_ / 4;
  int nwg1 = (F_/128) * rowTiles;   // 4352, %8==0
  int nwg2 = (D_/128) * rowTiles;   // 1088, %8==0
  unsigned short* Ybuf = (unsigned short*)Abuf;   // Abuf dead after GEMM1

  hipMemsetAsync(counts, 0, 512, stream);
  gate_kernel<<<(T + 3)/4, 256, 0, stream>>>(x, gw, tidx, tw, counts, T);
  scatgath_kernel<<<T, 128, 0, stream>>>(x, tidx, counts, cursors, tokSlot, Abuf);

  if (newPath){
    cvtw_kernel<<<2048, 256, 0, stream>>>(wfc, wA, n4);
    cvtw_kernel<<<2048, 256, 0, stream>>>(wpj, wB, n4);
    gemm_kernel<true, true><<<nwg1, 256, 0, stream>>>(
        Abuf, (const void*)wA, bfc, counts, (unsigned short*)Hbuf);
    gemm_kernel<true, false><<<nwg2, 256, 0, stream>>>(
        Hbuf, (const void*)wB, bpj, counts, Ybuf);
  } else if (midPath){
    cvtw_kernel<<<2048, 256, 0, stream>>>(wfc, wA, n4);
    gemm_kernel<true, true><<<nwg1, 256, 0, stream>>>(
        Abuf, (const void*)wA, bfc, counts, (unsigned short*)Hbuf);
    cvtw_kernel<<<2048, 256, 0, stream>>>(wpj, wA, n4);
    gemm_kernel<true, false><<<nwg2, 256, 0, stream>>>(
        Hbuf, (const void*)wA, bpj, counts, Ybuf);
  } else {
    gemm_kernel<false, true><<<nwg1, 256, 0, stream>>>(
        Abuf, (const void*)wfc, bfc, counts, (unsigned short*)Hbuf);
    gemm_kernel<false, false><<<nwg2, 256, 0, stream>>>(
        Hbuf, (const void*)wpj, bpj, counts, Ybuf);
  }
  combine_kernel<<<T, 256, 0, stream>>>(Ybuf, tidx, tw, tokSlot, bpj, out);
}

// Round 6
// 524.693 us; speedup vs baseline: 1.8286x; 1.4363x over previous
//
#include <hip/hip_runtime.h>
#include <hip/hip_bf16.h>

#define E_ 8
#define D_ 1024
#define F_ 4096
#define K_ 2

typedef __attribute__((ext_vector_type(8))) short short8;
typedef __attribute__((ext_vector_type(4))) float f32x4;

__device__ __forceinline__ unsigned f2bf(float f){
  union { __hip_bfloat16 h; unsigned short u; } c;
  c.h = __float2bfloat16(f);
  return (unsigned)c.u;
}

__device__ __forceinline__ float bf2f(unsigned u){
  union { float f; unsigned u; } c;
  c.u = u << 16;
  return c.f;
}

__device__ __forceinline__ float gelu_f(float v){
  const float c0 = 0.7978845608028654f;   // sqrt(2/pi)
  float z = c0 * (v + 0.044715f * v * v * v);
  float e = __expf(2.0f * z);
  float t = 1.0f - 2.0f / (1.0f + e);     // tanh(z), stable for |z| large
  return 0.5f * v * (1.0f + t);
}

__device__ __forceinline__ void gload16(const void* gsrc, void* ldst){
  __builtin_amdgcn_global_load_lds(
      (const __attribute__((address_space(1))) unsigned int*)gsrc,
      (__attribute__((address_space(3))) unsigned int*)ldst, 16, 0, 0);
}

// ---------------- gating: top-2 + softmax, NO atomics ----------------
__global__ void gate_kernel(const float* __restrict__ x, const float* __restrict__ gw,
                            int* __restrict__ tidx, float* __restrict__ tw, int T){
  int wid = threadIdx.x >> 6, lane = threadIdx.x & 63;
  int t = blockIdx.x * 4 + wid;
  if (t >= T) return;
  const float* xr = x + (size_t)t * D_;
  double acc[E_];
  #pragma unroll
  for (int e = 0; e < E_; ++e) acc[e] = 0.0;
  #pragma unroll
  for (int j = 0; j < 16; ++j){
    float xv = xr[j*64 + lane];
    #pragma unroll
    for (int e = 0; e < E_; ++e)
      acc[e] += (double)xv * (double)gw[e*D_ + j*64 + lane];
  }
  #pragma unroll
  for (int e = 0; e < E_; ++e){
    #pragma unroll
    for (int off = 32; off >= 1; off >>= 1)
      acc[e] += __shfl_xor(acc[e], off);
  }
  if (lane == 0){
    float l[E_];
    #pragma unroll
    for (int e = 0; e < E_; ++e) l[e] = (float)acc[e];
    int i0 = 0; float v0 = l[0];
    #pragma unroll
    for (int e = 1; e < E_; ++e) if (l[e] > v0){ v0 = l[e]; i0 = e; }
    int i1 = -1; float v1 = -1e30f;
    #pragma unroll
    for (int e = 0; e < E_; ++e) if (e != i0 && l[e] > v1){ v1 = l[e]; i1 = e; }
    float e1 = expf(v1 - v0);
    float s = 1.0f + e1;
    tidx[2*t] = i0; tidx[2*t+1] = i1;
    tw[2*t] = 1.0f / s; tw[2*t+1] = e1 / s;
  }
}

// ---------------- slot scan: deterministic histogram + prefix, single block ----------------
// Computes counts[e] and tokSlot[i] (stable order) with zero global atomics.
__global__ void slotscan_kernel(const int* __restrict__ tidx, int* __restrict__ counts,
                                int* __restrict__ tokSlot, int nAssign){
  __shared__ int cnt[256][E_];      // per-thread expert counts -> running cursors (8 KB)
  __shared__ int wtot[E_][4];       // per-wave totals -> per-wave offsets
  __shared__ int ebase[E_];         // 128-aligned expert base slots
  const int tid = threadIdx.x;
  const int lane = tid & 63, w = tid >> 6;
  const int per = (nAssign + 255) >> 8;
  const int base = tid * per;

  #pragma unroll
  for (int e = 0; e < E_; ++e) cnt[tid][e] = 0;
  for (int j = 0; j < per; ++j){
    int i = base + j;
    if (i < nAssign) cnt[tid][tidx[i]]++;
  }
  // wave-level exclusive scan per expert
  int excl[E_];
  #pragma unroll
  for (int e = 0; e < E_; ++e){
    int v = cnt[tid][e];
    int s = v;
    #pragma unroll
    for (int off = 1; off < 64; off <<= 1){
      int u = __shfl_up(s, off);
      if (lane >= off) s += u;
    }
    if (lane == 63) wtot[e][w] = s;
    excl[e] = s - v;
  }
  __syncthreads();
  if (tid == 0){
    int pre = 0;
    #pragma unroll
    for (int e = 0; e < E_; ++e){
      int tot = 0;
      #pragma unroll
      for (int ww = 0; ww < 4; ++ww){ int c = wtot[e][ww]; wtot[e][ww] = tot; tot += c; }
      counts[e] = tot;
      ebase[e] = pre;
      pre += (tot + 127) & ~127;
    }
  }
  __syncthreads();
  #pragma unroll
  for (int e = 0; e < E_; ++e)
    cnt[tid][e] = ebase[e] + wtot[e][w] + excl[e];
  for (int j = 0; j < per; ++j){
    int i = base + j;
    if (i < nAssign){
      int e = tidx[i];
      tokSlot[i] = cnt[tid][e]++;
    }
  }
}

// ---------------- fused gather: bf16 row copy to precomputed slots, no atomics ----------------
__global__ void scatgath_kernel(const float* __restrict__ x,
                                const int* __restrict__ tokSlot,
                                __hip_bfloat16* __restrict__ Abuf){
  int t = blockIdx.x;
  int s0 = tokSlot[K_*t], s1 = tokSlot[K_*t + 1];
  const float4* src = reinterpret_cast<const float4*>(x + (size_t)t * D_) + threadIdx.x*2;
  float4 v0 = src[0], v1 = src[1];
  uint4 p;
  p.x = f2bf(v0.x) | (f2bf(v0.y) << 16);
  p.y = f2bf(v0.z) | (f2bf(v0.w) << 16);
  p.z = f2bf(v1.x) | (f2bf(v1.y) << 16);
  p.w = f2bf(v1.z) | (f2bf(v1.w) << 16);
  *(reinterpret_cast<uint4*>(reinterpret_cast<unsigned short*>(Abuf) + (size_t)s0*D_) + threadIdx.x) = p;
  *(reinterpret_cast<uint4*>(reinterpret_cast<unsigned short*>(Abuf) + (size_t)s1*D_) + threadIdx.x) = p;
}

// ---------------- weight fp32 -> bf16 ----------------
__global__ void cvtw_kernel(const float* __restrict__ src, __hip_bfloat16* __restrict__ dst, int n4){
  int stride = gridDim.x * blockDim.x;
  for (int i = blockIdx.x * blockDim.x + threadIdx.x; i < n4; i += stride){
    float4 v = reinterpret_cast<const float4*>(src)[i];
    uint2 p;
    p.x = f2bf(v.x) | (f2bf(v.y) << 16);
    p.y = f2bf(v.z) | (f2bf(v.w) << 16);
    reinterpret_cast<uint2*>(dst)[i] = p;
  }
}

// ---------------- final combine: out[t] = sum_k w_k * (Y[slot_k] + b_proj[e_k]) ----------------
__global__ void combine_kernel(const unsigned short* __restrict__ Ybuf,
                               const int* __restrict__ tidx, const float* __restrict__ tw,
                               const int* __restrict__ tokSlot,
                               const float* __restrict__ bpj,
                               float* __restrict__ out){
  int t = blockIdx.x;
  int d = threadIdx.x * 4;
  int e0 = tidx[2*t], e1 = tidx[2*t+1];
  float w0 = tw[2*t], w1 = tw[2*t+1];
  int s0 = tokSlot[2*t], s1 = tokSlot[2*t+1];
  uint2 ya = *reinterpret_cast<const uint2*>(Ybuf + (size_t)s0*D_ + d);
  uint2 yb = *reinterpret_cast<const uint2*>(Ybuf + (size_t)s1*D_ + d);
  float4 b0 = *reinterpret_cast<const float4*>(bpj + (size_t)e0*D_ + d);
  float4 b1 = *reinterpret_cast<const float4*>(bpj + (size_t)e1*D_ + d);
  float4 r;
  r.x = w0*(bf2f(ya.x & 0xffffu) + b0.x) + w1*(bf2f(yb.x & 0xffffu) + b1.x);
  r.y = w0*(bf2f(ya.x >> 16)     + b0.y) + w1*(bf2f(yb.x >> 16)     + b1.y);
  r.z = w0*(bf2f(ya.y & 0xffffu) + b0.z) + w1*(bf2f(yb.y & 0xffffu) + b1.z);
  r.w = w0*(bf2f(ya.y >> 16)     + b0.w) + w1*(bf2f(yb.y >> 16)     + b1.w);
  *reinterpret_cast<float4*>(out + (size_t)t*D_ + d) = r;
}

// ---------------- 128x128 GEMM (m97 structure + XCD row-chunk swizzle) ----------------
// PH1: H = gelu(A wfc^T + b) -> bf16 Hbuf[slot][F]
// PH2: Y = H wproj^T         -> bf16 Ybuf[slot][D]   (bias+route applied in combine)
template<bool WB16, bool PH1>
__global__ __launch_bounds__(256, 4) void gemm_kernel(
    const __hip_bfloat16* __restrict__ Abuf,   // [rows][KA] bf16
    const void* __restrict__ W,                // [E][NT][KA] bf16 or fp32
    const float* __restrict__ bias,            // [E][NT] (PH1 only)
    const int* __restrict__ counts,
    unsigned short* __restrict__ Out16)
{
  constexpr int KA = PH1 ? D_ : F_;
  constexpr int NT = PH1 ? F_ : D_;
  constexpr int NK = KA / 64;
  constexpr int NX = NT / 128;

  __shared__ char sA[128*128];
  __shared__ char sB[128*128];

  // prefix over counts (128-aligned per-expert regions)
  int pre[E_]; int total = 0;
  #pragma unroll
  for (int i = 0; i < E_; ++i){ pre[i] = total; total += (counts[i] + 127) & ~127; }

  // bijective XCD row-chunk swizzle: XCD c = bid&7 owns a contiguous wgid chunk
  int q = gridDim.x >> 3;                       // gridDim.x divisible by 8
  int wgid = (blockIdx.x & 7) * q + (blockIdx.x >> 3);
  int yt = wgid / NX, xt = wgid - yt * NX;      // columns fastest within chunk
  int rowBase = yt * 128;
  if (rowBase >= total) return;
  int e = 0;
  #pragma unroll
  for (int i = 1; i < E_; ++i) if (rowBase >= pre[i]) e = i;
  int nBase = xt * 128;

  const int tid = threadIdx.x;
  const int wid = tid >> 6, lane = tid & 63;
  const int lr = lane & 15, lg = lane >> 4;
  const int wr = wid >> 1, wc = wid & 1;

  const unsigned short* Wb = (const unsigned short*)W;
  const float* Wf = (const float*)W;
  const size_t Wrow0 = (size_t)e * NT + nBase;

  f32x4 acc[4][4];
  #pragma unroll
  for (int m = 0; m < 4; ++m)
    #pragma unroll
    for (int n = 0; n < 4; ++n) acc[m][n] = (f32x4){0.f,0.f,0.f,0.f};

  for (int kt = 0; kt < NK; ++kt){
    int k0 = kt * 64;
    // ---- stage A tile via global_load_lds (linear dest, inverse-swizzled source) ----
    #pragma unroll
    for (int i = 0; i < 4; ++i){
      int flat = i*4096 + wid*1024 + lane*16;
      int row  = flat >> 7;
      int colb = flat & 127;
      int scol = colb ^ ((row & 7) << 4);
      const char* src = (const char*)(Abuf + (size_t)(rowBase + row) * KA + k0) + scol;
      gload16(src, sA + i*4096 + wid*1024);
    }
    // ---- stage B tile ----
    if constexpr (WB16){
      #pragma unroll
      for (int i = 0; i < 4; ++i){
        int flat = i*4096 + wid*1024 + lane*16;
        int row  = flat >> 7;
        int colb = flat & 127;
        int scol = colb ^ ((row & 7) << 4);
        const char* src = (const char*)(Wb + (Wrow0 + row) * KA + k0) + scol;
        gload16(src, sB + i*4096 + wid*1024);
      }
    } else {
      // reg-stage fp32 -> bf16, write-side swizzle
      #pragma unroll
      for (int i = 0; i < 8; ++i){
        int f4  = i*256 + tid;      // float4 index: 128 rows x 16 per row
        int row = f4 >> 4;
        int c4  = f4 & 15;
        float4 v = *reinterpret_cast<const float4*>(Wf + (Wrow0 + row) * KA + k0 + c4*4);
        uint2 p;
        p.x = f2bf(v.x) | (f2bf(v.y) << 16);
        p.y = f2bf(v.z) | (f2bf(v.w) << 16);
        int byte = row*128 + c4*8;
        *reinterpret_cast<uint2*>(sB + (byte ^ ((row & 7) << 4))) = p;
      }
    }
    __syncthreads();
    // ---- compute (swapped operands: each thread holds 4 contiguous output cols) ----
    #pragma unroll
    for (int ks = 0; ks < 2; ++ks){
      short8 a[4], b[4];
      #pragma unroll
      for (int m = 0; m < 4; ++m){
        int row = wr*64 + m*16 + lr;
        a[m] = *reinterpret_cast<const short8*>(sA + row*128 + ((ks*64 + lg*16) ^ ((row & 7) << 4)));
      }
      #pragma unroll
      for (int n = 0; n < 4; ++n){
        int row = wc*64 + n*16 + lr;
        b[n] = *reinterpret_cast<const short8*>(sB + row*128 + ((ks*64 + lg*16) ^ ((row & 7) << 4)));
      }
      #pragma unroll
      for (int m = 0; m < 4; ++m)
        #pragma unroll
        for (int n = 0; n < 4; ++n)
          acc[m][n] = __builtin_amdgcn_mfma_f32_16x16x32_bf16(b[n], a[m], acc[m][n], 0, 0, 0);
    }
    __syncthreads();
  }

  // epilogue: rows rowBase+wr*64+m*16+lr ; cols nBase+wc*64+n*16+lg*4+{0..3}
  int colBase = nBase + wc*64;
  if constexpr (PH1){
    #pragma unroll
    for (int n = 0; n < 4; ++n){
      int gc = colBase + n*16 + lg*4;
      float4 b4 = *reinterpret_cast<const float4*>(bias + (size_t)e*F_ + gc);
      #pragma unroll
      for (int m = 0; m < 4; ++m){
        int grow = rowBase + wr*64 + m*16 + lr;
        uint2 p;
        p.x = f2bf(gelu_f(acc[m][n][0] + b4.x)) | (f2bf(gelu_f(acc[m][n][1] + b4.y)) << 16);
        p.y = f2bf(gelu_f(acc[m][n][2] + b4.z)) | (f2bf(gelu_f(acc[m][n][3] + b4.w)) << 16);
        *reinterpret_cast<uint2*>(Out16 + (size_t)grow * F_ + gc) = p;
      }
    }
  } else {
    #pragma unroll
    for (int n = 0; n < 4; ++n){
      int gc = colBase + n*16 + lg*4;
      #pragma unroll
      for (int m = 0; m < 4; ++m){
        int grow = rowBase + wr*64 + m*16 + lr;
        uint2 p;
        p.x = f2bf(acc[m][n][0]) | (f2bf(acc[m][n][1]) << 16);
        p.y = f2bf(acc[m][n][2]) | (f2bf(acc[m][n][3]) << 16);
        *reinterpret_cast<uint2*>(Out16 + (size_t)grow * D_ + gc) = p;
      }
    }
  }
}

extern "C" void kernel_launch(void* const* d_in, const int* in_sizes, int n_in,
                              void* d_out, int out_size, void* d_ws, size_t ws_size,
                              hipStream_t stream){
  const float* x   = (const float*)d_in[0];
  const float* gw  = (const float*)d_in[1];
  const float* wfc = (const float*)d_in[2];
  const float* bfc = (const float*)d_in[3];
  const float* wpj = (const float*)d_in[4];
  const float* bpj = (const float*)d_in[5];
  float* out = (float*)d_out;

  int T = in_sizes[0] / D_;              // 8192
  int nAssign = T * K_;
  int nSlotsMax = nAssign + E_ * 128;    // 17408
  int rowTiles = nSlotsMax / 128;        // 136

  char* ws = (char*)d_ws;
  size_t o = 0;
  int*   tidx    = (int*)(ws + o); o += (size_t)nAssign * 4;
  float* tw      = (float*)(ws + o); o += (size_t)nAssign * 4;
  int*   counts  = (int*)(ws + o); o += 256;
  int*   tokSlot = (int*)(ws + o); o += (size_t)nAssign * 4;
  o = (o + 255) & ~(size_t)255;

  size_t abytes = (size_t)nSlotsMax * D_ * 2;   // Abuf; reused as Ybuf after GEMM1
  size_t hbytes = (size_t)nSlotsMax * F_ * 2;
  size_t wbytes = (size_t)E_ * F_ * D_ * 2;     // 67 MB per weight tensor (bf16)

  __hip_bfloat16* Abuf = (__hip_bfloat16*)(ws + o); o += abytes;
  __hip_bfloat16* Hbuf = (__hip_bfloat16*)(ws + o); o += hbytes;
  size_t o_w = o;
  __hip_bfloat16* wA = (__hip_bfloat16*)(ws + o_w);
  __hip_bfloat16* wB = (__hip_bfloat16*)(ws + o_w + wbytes);

  bool newPath = (ws_size >= o_w + 2*wbytes);   // ~313 MB: both weights converted upfront
  bool midPath = (ws_size >= o_w + wbytes);     // ~246 MB: one buffer, serial reuse
  // below that: fp32-weight GEMMs (~179 MB)

  int n4 = E_ * F_ * D_ / 4;
  int nwg1 = (F_/128) * rowTiles;   // 4352, %8==0
  int nwg2 = (D_/128) * rowTiles;   // 1088, %8==0
  unsigned short* Ybuf = (unsigned short*)Abuf;   // Abuf dead after GEMM1

  gate_kernel<<<(T + 3)/4, 256, 0, stream>>>(x, gw, tidx, tw, T);
  slotscan_kernel<<<1, 256, 0, stream>>>(tidx, counts, tokSlot, nAssign);
  scatgath_kernel<<<T, 128, 0, stream>>>(x, tokSlot, Abuf);

  if (newPath){
    cvtw_kernel<<<2048, 256, 0, stream>>>(wfc, wA, n4);
    cvtw_kernel<<<2048, 256, 0, stream>>>(wpj, wB, n4);
    gemm_kernel<true, true><<<nwg1, 256, 0, stream>>>(
        Abuf, (const void*)wA, bfc, counts, (unsigned short*)Hbuf);
    gemm_kernel<true, false><<<nwg2, 256, 0, stream>>>(
        Hbuf, (const void*)wB, bpj, counts, Ybuf);
  } else if (midPath){
    cvtw_kernel<<<2048, 256, 0, stream>>>(wfc, wA, n4);
    gemm_kernel<true, true><<<nwg1, 256, 0, stream>>>(
        Abuf, (const void*)wA, bfc, counts, (unsigned short*)Hbuf);
    cvtw_kernel<<<2048, 256, 0, stream>>>(wpj, wA, n4);
    gemm_kernel<true, false><<<nwg2, 256, 0, stream>>>(
        Hbuf, (const void*)wA, bpj, counts, Ybuf);
  } else {
    gemm_kernel<false, true><<<nwg1, 256, 0, stream>>>(
        Abuf, (const void*)wfc, bfc, counts, (unsigned short*)Hbuf);
    gemm_kernel<false, false><<<nwg2, 256, 0, stream>>>(
        Hbuf, (const void*)wpj, bpj, counts, Ybuf);
  }
  combine_kernel<<<T, 256, 0, stream>>>(Ybuf, tidx, tw, tokSlot, bpj, out);
}